// Round 1
// baseline (305.233 us; speedup 1.0000x reference)
//
#include <hip/hip_runtime.h>
#include <hip/hip_bf16.h>

// Problem constants from the reference: B=256, N=65536, fp32.
//   out[b, k, :] pairs consecutive elements of [real[b,:], imag[b,:]]
//   => reals occupy out floats [b*2N, b*2N+N), imags [b*2N+N, b*2N+2N).
// Each thread handles 4 complex elements (2x float4 loads per input,
// 1x float4 store to the real region + 1x float4 store to the imag region).

#define N_COMPLEX 65536           // per row
#define ROW_F4    (2 * N_COMPLEX / 4)   // out row length in float4 units = 32768
#define IMAG_OFF_F4 (N_COMPLEX / 4)     // 16384

__global__ __launch_bounds__(256) void cmul_kernel(
        const float4* __restrict__ a,
        const float4* __restrict__ b,
        float4* __restrict__ out) {
    const unsigned int t = blockIdx.x * blockDim.x + threadIdx.x;
    // thread t covers complex indices [4t, 4t+4) ; row = 4t / N = t >> 14
    const unsigned int row = t >> 14;
    const unsigned int n4  = t & 16383;         // (complex index % N) / 4

    const size_t in4 = (size_t)t * 2;           // float4 index into inputs
    const float4 a0 = a[in4];
    const float4 a1 = a[in4 + 1];
    const float4 b0 = b[in4];
    const float4 b1 = b[in4 + 1];

    float4 re, im;
    re.x = a0.x * b0.x - a0.y * b0.y;
    im.x = a0.y * b0.x + a0.x * b0.y;
    re.y = a0.z * b0.z - a0.w * b0.w;
    im.y = a0.w * b0.z + a0.z * b0.w;
    re.z = a1.x * b1.x - a1.y * b1.y;
    im.z = a1.y * b1.x + a1.x * b1.y;
    re.w = a1.z * b1.z - a1.w * b1.w;
    im.w = a1.w * b1.z + a1.z * b1.w;

    const size_t base = (size_t)row * ROW_F4 + n4;
    out[base]               = re;
    out[base + IMAG_OFF_F4] = im;
}

extern "C" void kernel_launch(void* const* d_in, const int* in_sizes, int n_in,
                              void* d_out, int out_size, void* d_ws, size_t ws_size,
                              hipStream_t stream) {
    const float4* a = (const float4*)d_in[0];
    const float4* b = (const float4*)d_in[1];
    float4* out = (float4*)d_out;

    // total complex = out_size/2 ; threads = complex/4
    const int threads_total = out_size / 8;     // 4,194,304
    const int block = 256;
    const int grid = threads_total / block;     // 16384
    cmul_kernel<<<grid, block, 0, stream>>>(a, b, out);
}